// Round 4
// baseline (77.781 us; speedup 1.0000x reference)
//
#include <hip/hip_runtime.h>

#define S_DEPTH 128
#define N_RES   512
#define E_DIM   256
#define P_DIM   32
#define C_DIM   128

typedef short bh8 __attribute__((ext_vector_type(8)));   // 8 x bf16 (raw shorts)
typedef short sh2 __attribute__((ext_vector_type(2)));   // 2 x bf16
typedef float fx4 __attribute__((ext_vector_type(4)));   // MFMA f32 accumulator

__device__ __forceinline__ unsigned short f2bf(float x){
    unsigned int u = __builtin_bit_cast(unsigned int, x);
    u += 0x7fffu + ((u >> 16) & 1u);          // round-to-nearest-even
    return (unsigned short)(u >> 16);
}

// ---------------------------------------------------------------------------
// K0: transpose weights to bf16. 48 blocks x 256 = 12288 threads = 8192+4096.
//   WaT/WbT: [P][E]  (E contiguous)   WpT: [C][P]  (P contiguous)
// ---------------------------------------------------------------------------
__global__ void prep_kernel(const float* __restrict__ Wa, const float* __restrict__ Wb,
                            const float* __restrict__ Wp,
                            unsigned short* __restrict__ WaT, unsigned short* __restrict__ WbT,
                            unsigned short* __restrict__ WpT){
    int tid = blockIdx.x * 256 + threadIdx.x;
    if (tid < 8192){
        int p = tid >> 8, e = tid & 255;
        WaT[tid] = f2bf(Wa[e * P_DIM + p]);
        WbT[tid] = f2bf(Wb[e * P_DIM + p]);
    } else {
        int i = tid - 8192;
        int c = i >> 5, p = i & 31;
        WpT[i] = f2bf(Wp[p * C_DIM + c]);
    }
}

// ---------------------------------------------------------------------------
// K1: LayerNorm + dual projection. Grid (512 n, 2 s-halves), 256 thr, 32 KB LDS.
//   Phase 1: LN of 64 rows -> bf16 swizzled LDS (unroll 4 keeps loads in flight).
//   Phase 2: D[s][p] = xn(s,k) @ W(k,p) via MFMA (A = x-frag, B = W-frag).
//   Epilogue: 8-B packed stores of 4 consecutive s into aT/bT [p][n][s].
// ---------------------------------------------------------------------------
__global__ __launch_bounds__(256, 4) void lnproj_kernel(
    const float* __restrict__ x, const float* __restrict__ gamma, const float* __restrict__ beta,
    const unsigned short* __restrict__ WaT, const unsigned short* __restrict__ WbT,
    const float* __restrict__ ba, const float* __restrict__ bb,
    unsigned short* __restrict__ aT, unsigned short* __restrict__ bT)
{
    __shared__ __align__(16) char smem[64 * 512];      // 64 s-rows x 512 B = 32 KB
    const int n0   = blockIdx.x;
    const int sh   = blockIdx.y;                       // s-half (0/1)
    const int tid  = threadIdx.x;
    const int lane = tid & 63;
    const int w    = tid >> 6;                         // 4 waves
    const int l15  = lane & 15;
    const int lq   = lane >> 4;

    const float4 g4 = *(const float4*)(gamma + lane * 4);
    const float4 b4 = *(const float4*)(beta  + lane * 4);

    // ---- phase 1: LN, 16 rows per wave ----
    #pragma unroll 4
    for (int rr = 0; rr < 16; ++rr){
        int s_loc = w * 16 + rr;
        int s     = sh * 64 + s_loc;
        float4 v = *(const float4*)(x + ((size_t)(s * N_RES + n0)) * E_DIM + lane * 4);
        float sum = v.x + v.y + v.z + v.w;
        float sq  = v.x*v.x + v.y*v.y + v.z*v.z + v.w*v.w;
        #pragma unroll
        for (int m = 1; m < 64; m <<= 1){
            sum += __shfl_xor(sum, m);
            sq  += __shfl_xor(sq,  m);
        }
        float mu  = sum * (1.0f / E_DIM);
        float inv = rsqrtf(sq * (1.0f / E_DIM) - mu * mu + 1e-5f);
        ushort4 pk;
        pk.x = f2bf((v.x - mu) * inv * g4.x + b4.x);
        pk.y = f2bf((v.y - mu) * inv * g4.y + b4.y);
        pk.z = f2bf((v.z - mu) * inv * g4.z + b4.z);
        pk.w = f2bf((v.w - mu) * inv * g4.w + b4.w);
        int boff = s_loc * 512 + lane * 8;
        boff ^= (s_loc & 7) << 4;                      // 16-B-granule XOR swizzle
        *(ushort4*)(smem + boff) = pk;
    }
    __syncthreads();

    // ---- phase 2: wave w owns s-tile w (16 s-rows). D[s][p]. ----
    fx4 accA[2], accB[2];                              // [pt]
    #pragma unroll
    for (int pt = 0; pt < 2; ++pt){
        accA[pt] = fx4{0.f, 0.f, 0.f, 0.f};
        accB[pt] = fx4{0.f, 0.f, 0.f, 0.f};
    }
    const int srow = w * 16 + l15;

    #pragma unroll
    for (int ks = 0; ks < 8; ++ks){                    // K = 256 = 8 x 32
        int boff = srow * 512 + (ks * 32 + lq * 8) * 2;
        boff ^= (srow & 7) << 4;
        bh8 xf = *(const bh8*)(smem + boff);           // A: row s, 8 contig k
        #pragma unroll
        for (int pt = 0; pt < 2; ++pt){
            int off = (pt * 16 + l15) * E_DIM + ks * 32 + lq * 8;   // B: col p
            bh8 wa = *(const bh8*)(WaT + off);
            bh8 wb = *(const bh8*)(WbT + off);
            accA[pt] = __builtin_amdgcn_mfma_f32_16x16x32_bf16(xf, wa, accA[pt], 0, 0, 0);
            accB[pt] = __builtin_amdgcn_mfma_f32_16x16x32_bf16(xf, wb, accB[pt], 0, 0, 0);
        }
    }

    // ---- epilogue: D col = p (l15), row = s (lq*4+j) -> packed 8-B stores ----
    #pragma unroll
    for (int pt = 0; pt < 2; ++pt){
        int p = pt * 16 + l15;
        float bav = ba[p], bbv = bb[p];
        int s_base = sh * 64 + w * 16 + lq * 4;
        size_t o = ((size_t)p * N_RES + n0) * S_DEPTH + s_base;
        ushort4 ua, ub;
        ua.x = f2bf(accA[pt][0] + bav); ua.y = f2bf(accA[pt][1] + bav);
        ua.z = f2bf(accA[pt][2] + bav); ua.w = f2bf(accA[pt][3] + bav);
        ub.x = f2bf(accB[pt][0] + bbv); ub.y = f2bf(accB[pt][1] + bbv);
        ub.z = f2bf(accB[pt][2] + bbv); ub.w = f2bf(accB[pt][3] + bbv);
        *(ushort4*)(aT + o) = ua;
        *(ushort4*)(bT + o) = ub;
    }
}

// ---------------------------------------------------------------------------
// K2: fused batched outer (mean over S) + Wp projection + bias.
//   512 blocks (16 tn x 32 tm), 32x16 nm tile, 512 thr (8 waves), 32 KB LDS
//   -> 2 blocks/CU co-resident: one block's store phase overlaps the other's
//   load/MFMA phase. Wave w owns p = 4w..4w+3.
//   LDS transpose via paired b32 ops, slot swizzle u ^ ((nm>>1)&7) ^
//   (((nm>>6)&1)<<3): verified 2 lanes/bank (free) on write AND read.
// ---------------------------------------------------------------------------
__global__ __launch_bounds__(512, 4) void outer_kernel(
    const unsigned short* __restrict__ aT, const unsigned short* __restrict__ bT,
    const unsigned short* __restrict__ WpT, const float* __restrict__ bp,
    float* __restrict__ out)
{
    __shared__ __align__(16) char smem[512 * 64];      // [nm=512][16 units x 4 B]
    const int tn = blockIdx.x >> 5, tm = blockIdx.x & 31;
    const int n0 = tn * 32, m0 = tm * 16;
    const int tid  = threadIdx.x;
    const int lane = tid & 63;
    const int w    = tid >> 6;                         // 8 waves
    const int l15  = lane & 15;
    const int lq   = lane >> 4;

    // ---- stage 1: outer products, 4 p per wave, all accs live ----
    fx4 acc[4][2];                                     // [q][ti(n)]
    #pragma unroll
    for (int q = 0; q < 4; ++q)
        #pragma unroll
        for (int ti = 0; ti < 2; ++ti)
            acc[q][ti] = fx4{0.f, 0.f, 0.f, 0.f};

    #pragma unroll
    for (int ks = 0; ks < 4; ++ks){                    // K = S = 128 = 4 x 32
        #pragma unroll
        for (int q = 0; q < 4; ++q){
            int p = w * 4 + q;
            size_t kbase = (size_t)p * N_RES * S_DEPTH + ks * 32 + lq * 8;
            bh8 bfv = *(const bh8*)(bT + kbase + (size_t)(m0 + l15) * S_DEPTH);
            bh8 af0 = *(const bh8*)(aT + kbase + (size_t)(n0 + l15) * S_DEPTH);
            bh8 af1 = *(const bh8*)(aT + kbase + (size_t)(n0 + 16 + l15) * S_DEPTH);
            acc[q][0] = __builtin_amdgcn_mfma_f32_16x16x32_bf16(af0, bfv, acc[q][0], 0, 0, 0);
            acc[q][1] = __builtin_amdgcn_mfma_f32_16x16x32_bf16(af1, bfv, acc[q][1], 0, 0, 0);
        }
    }

    // ---- stage 1b: LDS transpose. unit u=2w+h holds p {4w+2h, 4w+2h+1} ----
    #pragma unroll
    for (int ti = 0; ti < 2; ++ti)
        #pragma unroll
        for (int j = 0; j < 4; ++j){
            int nm  = (ti * 16 + lq * 4 + j) * 16 + l15;   // nloc*16 + mloc
            int swz = ((nm >> 1) & 7) ^ (((nm >> 6) & 1) << 3);
            #pragma unroll
            for (int h = 0; h < 2; ++h){
                sh2 v;
                v[0] = (short)f2bf(acc[2*h  ][ti][j] * (1.0f / S_DEPTH));
                v[1] = (short)f2bf(acc[2*h+1][ti][j] * (1.0f / S_DEPTH));
                int u = 2 * w + h;
                *(sh2*)(smem + nm * 64 + ((u ^ swz) << 2)) = v;
            }
        }
    __syncthreads();

    // ---- stage 2: project P -> C, fused bias, f32 stores ----
    bh8   wpf[8];
    float bpv[8];
    #pragma unroll
    for (int ct = 0; ct < 8; ++ct){
        wpf[ct] = *(const bh8*)(WpT + (ct * 16 + l15) * P_DIM + lq * 8);  // B: col c, k=p
        bpv[ct] = bp[ct * 16 + l15];
    }
    #pragma unroll
    for (int mi = 0; mi < 4; ++mi){
        int mt  = w * 4 + mi;                          // 32 row-tiles / 8 waves
        int nm  = mt * 16 + l15;
        int swz = ((nm >> 1) & 7) ^ (((nm >> 6) & 1) << 3);
        bh8 of;                                        // A: row nm, k = p = lq*8..lq*8+7
        #pragma unroll
        for (int i = 0; i < 4; ++i){
            int u = 4 * lq + i;
            sh2 v = *(const sh2*)(smem + nm * 64 + ((u ^ swz) << 2));
            of[2*i]   = v[0];
            of[2*i+1] = v[1];
        }
        #pragma unroll
        for (int ct = 0; ct < 8; ++ct){
            fx4 d = __builtin_amdgcn_mfma_f32_16x16x32_bf16(
                        of, wpf[ct], fx4{0.f, 0.f, 0.f, 0.f}, 0, 0, 0);
            // D row r=lq*4+j -> n = n0+mt, m = m0+r; col c = ct*16+l15
            float* po = out + (((size_t)(n0 + mt) * N_RES) + m0) * C_DIM + ct * 16 + l15;
            #pragma unroll
            for (int j = 0; j < 4; ++j)
                po[(size_t)(lq * 4 + j) * C_DIM] = d[j] + bpv[ct];
        }
    }
}

// ---------------------------------------------------------------------------
extern "C" void kernel_launch(void* const* d_in, const int* in_sizes, int n_in,
                              void* d_out, int out_size, void* d_ws, size_t ws_size,
                              hipStream_t stream){
    const float* msa   = (const float*)d_in[0];
    const float* gamma = (const float*)d_in[1];
    const float* beta  = (const float*)d_in[2];
    const float* Wa    = (const float*)d_in[3];
    const float* ba    = (const float*)d_in[4];
    const float* Wb    = (const float*)d_in[5];
    const float* bb    = (const float*)d_in[6];
    const float* Wp    = (const float*)d_in[7];
    const float* bp    = (const float*)d_in[8];
    float* out = (float*)d_out;

    // workspace (ushort elems): aT | bT | WaT | WbT | WpT
    unsigned short* ws  = (unsigned short*)d_ws;
    unsigned short* aT  = ws;                        // 32*512*128 = 2097152
    unsigned short* bT  = ws + 2097152;
    unsigned short* WaT = ws + 4194304;              // 8192
    unsigned short* WbT = WaT + 8192;                // 8192
    unsigned short* WpT = WbT + 8192;                // 4096

    prep_kernel<<<48, 256, 0, stream>>>(Wa, Wb, Wp, WaT, WbT, WpT);
    lnproj_kernel<<<dim3(N_RES, 2), 256, 0, stream>>>(msa, gamma, beta, WaT, WbT, ba, bb, aT, bT);
    outer_kernel<<<512, 512, 0, stream>>>(aT, bT, WpT, bp, out);
}